// Round 16
// baseline (395.427 us; speedup 1.0000x reference)
//
#include <hip/hip_runtime.h>
#include <hip/hip_bf16.h>
#include <math.h>

#define N_NODES 50000
#define F_IN 256
#define H1 128
#define C_OUT 40
#define L1W 384   // 3*H1
#define L2W 120   // 3*C_OUT
#define L2WP 128  // padded
#define NBUK 196  // ceil(50000/256) dst buckets of 256 nodes
#define NBLK1 256 // phase-1 blocks

typedef __attribute__((ext_vector_type(8))) short short8;
typedef __attribute__((ext_vector_type(4))) float f32x4;
typedef __attribute__((ext_vector_type(2))) float f32x2;
typedef __attribute__((ext_vector_type(4))) unsigned short us4;

__device__ inline unsigned short f2bf(float f) {
    union { float f; unsigned int u; } x;
    x.f = f;
    unsigned int u = x.u;
    return (unsigned short)((u + 0x7FFF + ((u >> 16) & 1)) >> 16);
}
__device__ inline float bf2f(unsigned short u) {
    union { unsigned int u; float f; } x;
    x.u = (unsigned int)u << 16;
    return x.f;
}
__device__ inline unsigned int pack_fp8x4(float a, float b, float c, float d) {
    int v = 0;
    v = __builtin_amdgcn_cvt_pk_fp8_f32(a, b, v, false);  // bytes 0,1
    v = __builtin_amdgcn_cvt_pk_fp8_f32(c, d, v, true);   // bytes 2,3
    return (unsigned int)v;
}
__device__ inline unsigned char pack_fp8x1(float a) {
    return (unsigned char)(__builtin_amdgcn_cvt_pk_fp8_f32(a, a, 0, false) & 0xFF);
}
// decode 4B edge record {w:bf16:16 | src:16}
#define EDGE_S(r) ((int)((r) & 0xFFFFu))
#define EDGE_W(r) bf2f((unsigned short)((r) >> 16))

// ---------------- edge-index dtype detection --------------------------------

__global__ void detect_k(const int* __restrict__ ei, int* __restrict__ flag) {
    __shared__ int any;
    if (threadIdx.x == 0) any = 0;
    __syncthreads();
    int v = 0;
    for (int r = 0; r < 4; r++) {
        int e = threadIdx.x + r * 256;
        v |= ei[e * 2 + 1];
    }
    if (v != 0) atomicOr(&any, 1);
    __syncthreads();
    if (threadIdx.x == 0) *flag = any;  // 1 => int32 layout, 0 => int64
}

// ---------------- per-node degree histogram ---------------------------------

__global__ void hist_k(const int* __restrict__ ei, const int* __restrict__ flag,
                       int* __restrict__ cnt, int E) {
    int base = (blockIdx.x * 256 + threadIdx.x) * 4;
    if (base >= E) return;
    if (base + 4 <= E) {
        int d0, d1, d2, d3;
        if (*flag) {
            int4 dv = *(const int4*)(ei + E + base);
            d0 = dv.x; d1 = dv.y; d2 = dv.z; d3 = dv.w;
        } else {
            const long long* e64 = (const long long*)ei;
            longlong2 a = *(const longlong2*)(e64 + E + base);
            longlong2 b = *(const longlong2*)(e64 + E + base + 2);
            d0 = (int)a.x; d1 = (int)a.y; d2 = (int)b.x; d3 = (int)b.y;
        }
        atomicAdd(&cnt[d0], 1);
        atomicAdd(&cnt[d1], 1);
        atomicAdd(&cnt[d2], 1);
        atomicAdd(&cnt[d3], 1);
    } else {
        for (int e = base; e < E; e++) {
            int d = (*flag) ? ei[E + e] : (int)((const long long*)ei)[E + e];
            atomicAdd(&cnt[d], 1);
        }
    }
}

__global__ void dinv_k(const int* __restrict__ cnt, float* __restrict__ dinv, int n) {
    int i = blockIdx.x * 256 + threadIdx.x;
    if (i < n) dinv[i] = rsqrtf((float)cnt[i] + 1.0f);
}

// ---------------- generic 3-level exclusive scan ----------------------------

__global__ __launch_bounds__(256) void scan1_k(const int* __restrict__ cnt,
                                               int* __restrict__ bsum, int n) {
    int t = threadIdx.x;
    int i = blockIdx.x * 256 + t;
    int v = (i < n) ? cnt[i] : 0;
    for (int off = 32; off; off >>= 1) v += __shfl_down(v, off, 64);
    __shared__ int ws[4];
    if ((t & 63) == 0) ws[t >> 6] = v;
    __syncthreads();
    if (t == 0) bsum[blockIdx.x] = ws[0] + ws[1] + ws[2] + ws[3];
}

__global__ __launch_bounds__(256) void scan2_k(int* __restrict__ bsum,
                                               int* __restrict__ btot, int nb) {
    __shared__ int s[256];
    int t = threadIdx.x;
    int v = (t < nb) ? bsum[t] : 0;
    s[t] = v;
    __syncthreads();
    for (int off = 1; off < 256; off <<= 1) {
        int u = (t >= off) ? s[t - off] : 0;
        __syncthreads();
        s[t] += u;
        __syncthreads();
    }
    if (t < nb) bsum[t] = s[t] - v;  // exclusive
    if (t == nb - 1) *btot = s[t];
}

__global__ __launch_bounds__(256) void scan3_k(const int* __restrict__ cnt,
                                               const int* __restrict__ bsum,
                                               int* __restrict__ rowptr,
                                               int* __restrict__ fill, int n) {
    __shared__ int s[256];
    int t = threadIdx.x;
    int i = blockIdx.x * 256 + t;
    int v = (i < n) ? cnt[i] : 0;
    s[t] = v;
    __syncthreads();
    for (int off = 1; off < 256; off <<= 1) {
        int u = (t >= off) ? s[t - off] : 0;
        __syncthreads();
        s[t] += u;
        __syncthreads();
    }
    if (i < n) {
        int excl = s[t] - v + bsum[blockIdx.x];
        rowptr[i] = excl;
        fill[i] = excl;
    }
}

// ---------------- two-phase binned scatter ----------------------------------

__global__ __launch_bounds__(256) void hist2_k(const int* __restrict__ ei,
                                               const int* __restrict__ flag,
                                               int* __restrict__ cnt2, int E) {
    __shared__ int lcnt[NBUK];
    int t = threadIdx.x, blk = blockIdx.x;
    for (int j = t; j < NBUK; j += 256) lcnt[j] = 0;
    __syncthreads();
    int chunk = (E + NBLK1 - 1) / NBLK1;
    int beg = blk * chunk, end = min(beg + chunk, E);
    bool i32 = (*flag) != 0;
    const long long* e64 = (const long long*)ei;
    for (int e = beg + t; e < end; e += 256) {
        int d = i32 ? ei[E + e] : (int)e64[E + e];
        atomicAdd(&lcnt[d >> 8], 1);
    }
    __syncthreads();
    for (int j = t; j < NBUK; j += 256) cnt2[j * NBLK1 + blk] = lcnt[j];  // bucket-major
}

__global__ __launch_bounds__(256) void stage_k(const int* __restrict__ ei,
                                               const int* __restrict__ flag,
                                               const int* __restrict__ off2,
                                               unsigned int* __restrict__ stage, int E) {
    __shared__ int lcur[NBUK];
    int t = threadIdx.x, blk = blockIdx.x;
    for (int j = t; j < NBUK; j += 256) lcur[j] = off2[j * NBLK1 + blk];
    __syncthreads();
    int chunk = (E + NBLK1 - 1) / NBLK1;
    int beg = blk * chunk, end = min(beg + chunk, E);
    bool i32 = (*flag) != 0;
    const long long* e64 = (const long long*)ei;
    for (int e = beg + t; e < end; e += 256) {
        int s, d;
        if (i32) { s = ei[e]; d = ei[E + e]; }
        else { s = (int)e64[e]; d = (int)e64[E + e]; }
        int b = d >> 8;
        int pos = atomicAdd(&lcur[b], 1);
        stage[pos] = ((unsigned int)(d & 255) << 16) | (unsigned int)s;
    }
}

__global__ __launch_bounds__(256) void scatter2_k(const unsigned int* __restrict__ stage,
                                                  const int* __restrict__ off2,
                                                  const int* __restrict__ rowptr,
                                                  const float* __restrict__ dinv,
                                                  unsigned int* __restrict__ csr,
                                                  int E, int n) {
    __shared__ int lfill[256];
    int b = blockIdx.x, t = threadIdx.x;
    int node0 = b << 8;
    int node = node0 + t;
    lfill[t] = (node < n) ? rowptr[node] : 0;
    __syncthreads();
    int segBeg = off2[b * NBLK1];
    int segEnd = (b == NBUK - 1) ? E : off2[(b + 1) * NBLK1];
    for (int e = segBeg + t; e < segEnd; e += 256) {
        unsigned int rec = stage[e];
        int dl = rec >> 16;
        int s = rec & 0xFFFF;
        int d = node0 + dl;
        float w = dinv[s] * dinv[d];
        int pos = atomicAdd(&lfill[dl], 1);
        csr[pos] = ((unsigned int)f2bf(w) << 16) | (unsigned int)s;
    }
}

// ---------------- weight packing (bf16, B-fragment layout) ------------------

__global__ void pack1b_k(const float* __restrict__ w0, const float* __restrict__ w1,
                         const float* __restrict__ w2, unsigned short* __restrict__ Bp) {
    int idx = blockIdx.x * 256 + threadIdx.x;
    if (idx >= (F_IN / 32) * L1W * 32) return;
    int kk = idx & 31;
    int nn = (idx >> 5) % L1W;
    int kt = idx / (L1W * 32);
    int k = kt * 32 + kk;
    int p = nn >> 7, c = nn & 127;
    const float* w = (p == 0) ? w0 : (p == 1) ? w1 : w2;
    Bp[idx] = f2bf(w[k * H1 + c]);
}

__global__ void pack2b_k(const float* __restrict__ w0, const float* __restrict__ w1,
                         const float* __restrict__ w2, unsigned short* __restrict__ Bp) {
    int idx = blockIdx.x * 256 + threadIdx.x;
    if (idx >= (L1W / 32) * L2WP * 32) return;
    int kk = idx & 31;
    int nn = (idx >> 5) & (L2WP - 1);
    int kt = idx >> 12;  // 128*32 = 4096
    int k = kt * 32 + kk;
    unsigned short v = 0;
    if (nn < L2W) {
        int p = nn / 40, c = nn % 40;
        const float* w = (p == 0) ? w0 : (p == 1) ? w1 : w2;
        v = f2bf(w[k * C_OUT + c]);
    }
    Bp[idx] = v;
}

// ---------------- layer-1 GEMM, col-split halves ----------------------------
// Block = 64 rows x 192 cols (half h = blockIdx.y). Wave = 16 rows x 192 cols
// (12 accs). LDS 2 x 12 KB. h=0: cols 0..191 -> Hb relu (0..127) + Y8 bytes
// m*16..+3 (s=8..11). h=1: cols 192..383 -> Y8 bytes m*16+4..+15 (s=12..23).

__global__ __launch_bounds__(256, 6) void mgemm1_k(const float* __restrict__ A,
                                                   const unsigned short* __restrict__ Bp,
                                                   const float* __restrict__ b1,
                                                   unsigned short* __restrict__ Hb,
                                                   unsigned char* __restrict__ Y8, int N) {
    __shared__ unsigned short Bs[2][192 * 32];  // 2 x 12 KB
    int tid = threadIdx.x;
    int h = blockIdx.y;
    int col0 = h * 192;
    int wave = tid >> 6, lane = tid & 63;
    int m = lane & 15, kq = lane >> 4;
    int row0 = blockIdx.x * 64 + wave * 16;
    int arow = row0 + m;
    if (arow >= N) arow = N - 1;  // clamped duplicate; stores guarded
    const float* Ap = A + (size_t)arow * F_IN + kq * 8;

    f32x4 acc[12];
#pragma unroll
    for (int s = 0; s < 12; s++) acc[s] = (f32x4){0.f, 0.f, 0.f, 0.f};

    short8 breg[3];
    float4 af0, af1;
#pragma unroll
    for (int c = 0; c < 3; c++) {
        int t = tid + c * 256;
        int cl = t >> 2, pp = t & 3;
        breg[c] = *(const short8*)(Bp + ((size_t)(col0 + cl)) * 32 + pp * 8);
    }
    af0 = *(const float4*)(Ap);
    af1 = *(const float4*)(Ap + 4);
#pragma unroll
    for (int c = 0; c < 3; c++) {
        int t = tid + c * 256;
        int cl = t >> 2, pp = t & 3;
        *(short8*)(&Bs[0][cl * 32 + ((pp ^ ((cl >> 1) & 3)) << 3)]) = breg[c];
    }
    __syncthreads();

    for (int kt = 0; kt < F_IN / 32; kt++) {
        short8 a;
        a[0] = (short)f2bf(af0.x); a[1] = (short)f2bf(af0.y);
        a[2] = (short)f2bf(af0.z); a[3] = (short)f2bf(af0.w);
        a[4] = (short)f2bf(af1.x); a[5] = (short)f2bf(af1.y);
        a[6] = (short)f2bf(af1.z); a[7] = (short)f2bf(af1.w);
        if (kt < F_IN / 32 - 1) {
            const unsigned short* Bn = Bp + (size_t)(kt + 1) * L1W * 32;
#pragma unroll
            for (int c = 0; c < 3; c++) {
                int t = tid + c * 256;
                int cl = t >> 2, pp = t & 3;
                breg[c] = *(const short8*)(Bn + ((size_t)(col0 + cl)) * 32 + pp * 8);
            }
            af0 = *(const float4*)(Ap + (kt + 1) * 32);
            af1 = *(const float4*)(Ap + (kt + 1) * 32 + 4);
        }
        const unsigned short* Bbuf = Bs[kt & 1];
#pragma unroll
        for (int s = 0; s < 12; s++) {
            int cl = s * 16 + m;
            short8 b = *(const short8*)(&Bbuf[cl * 32 + ((kq ^ ((cl >> 1) & 3)) << 3)]);
            acc[s] = __builtin_amdgcn_mfma_f32_16x16x32_bf16(a, b, acc[s], 0, 0, 0);
        }
        if (kt < F_IN / 32 - 1) {
            int nb = (kt + 1) & 1;
#pragma unroll
            for (int c = 0; c < 3; c++) {
                int t = tid + c * 256;
                int cl = t >> 2, pp = t & 3;
                *(short8*)(&Bs[nb][cl * 32 + ((pp ^ ((cl >> 1) & 3)) << 3)]) = breg[c];
            }
        }
        __syncthreads();
    }
    int crow = row0 + kq * 4;
    if (h == 0) {
        // cols 0..127 -> Hb bf16 relu
#pragma unroll
        for (int s = 0; s < 8; s++) {
            int col = s * 16 + m;
            float bias = b1[col];
#pragma unroll
            for (int r = 0; r < 4; r++) {
                int row = crow + r;
                if (row < N) Hb[(size_t)row * L1W + col] = f2bf(fmaxf(acc[s][r] + bias, 0.f));
            }
        }
        // cols 128..191 = s_global 8..11 -> Y8 bytes m*16..+3
#pragma unroll
        for (int r = 0; r < 4; r++) {
            int row = crow + r;
            if (row < N) {
                unsigned int u = pack_fp8x4(acc[8][r], acc[9][r], acc[10][r], acc[11][r]);
                *(unsigned int*)(Y8 + (size_t)row * 256 + m * 16) = u;
            }
        }
    } else {
        // cols 192..383 = s_global 12..23 -> Y8 bytes m*16+4..+15
#pragma unroll
        for (int r = 0; r < 4; r++) {
            int row = crow + r;
            if (row < N) {
                unsigned int u0 = pack_fp8x4(acc[0][r], acc[1][r], acc[2][r], acc[3][r]);
                unsigned int u1 = pack_fp8x4(acc[4][r], acc[5][r], acc[6][r], acc[7][r]);
                unsigned int u2 = pack_fp8x4(acc[8][r], acc[9][r], acc[10][r], acc[11][r]);
                unsigned char* dst = Y8 + (size_t)row * 256 + m * 16;
                *(unsigned int*)(dst + 4) = u0;
                *(unsigned int*)(dst + 8) = u1;
                *(unsigned int*)(dst + 12) = u2;
            }
        }
    }
}

// ---------------- layer-2 GEMM, col-split halves ----------------------------
// Block = 64 rows x 64 cols (half h). Wave = 16 rows x 64 cols (4 accs).
// h=0: Ub bf16 cols 0..47 + U8 bytes m*8..+3 (s=0..3). h=1: U8 bytes m*8+4..+7.

__global__ __launch_bounds__(256, 6) void mgemm2_k(const unsigned short* __restrict__ A,
                                                   const unsigned short* __restrict__ Bp,
                                                   unsigned short* __restrict__ Ub,
                                                   unsigned char* __restrict__ U8, int N) {
    __shared__ unsigned short Bs[2][64 * 32];  // 2 x 4 KB
    int tid = threadIdx.x;
    int h = blockIdx.y;
    int col0 = h * 64;
    int wave = tid >> 6, lane = tid & 63;
    int m = lane & 15, kq = lane >> 4;
    int row0 = blockIdx.x * 64 + wave * 16;
    int arow = row0 + m;
    if (arow >= N) arow = N - 1;
    const unsigned short* Ap = A + (size_t)arow * L1W + kq * 8;

    f32x4 acc[4];
#pragma unroll
    for (int s = 0; s < 4; s++) acc[s] = (f32x4){0.f, 0.f, 0.f, 0.f};

    short8 breg;
    short8 areg;
    {
        int cl = tid >> 2, pp = tid & 3;
        breg = *(const short8*)(Bp + ((size_t)(col0 + cl)) * 32 + pp * 8);
    }
    areg = *(const short8*)(Ap);
    {
        int cl = tid >> 2, pp = tid & 3;
        *(short8*)(&Bs[0][cl * 32 + ((pp ^ ((cl >> 1) & 3)) << 3)]) = breg;
    }
    __syncthreads();

    for (int kt = 0; kt < L1W / 32; kt++) {
        short8 a = areg;
        if (kt < L1W / 32 - 1) {
            const unsigned short* Bn = Bp + (size_t)(kt + 1) * L2WP * 32;
            int cl = tid >> 2, pp = tid & 3;
            breg = *(const short8*)(Bn + ((size_t)(col0 + cl)) * 32 + pp * 8);
            areg = *(const short8*)(Ap + (kt + 1) * 32);
        }
        const unsigned short* Bbuf = Bs[kt & 1];
#pragma unroll
        for (int s = 0; s < 4; s++) {
            int cl = s * 16 + m;
            short8 b = *(const short8*)(&Bbuf[cl * 32 + ((kq ^ ((cl >> 1) & 3)) << 3)]);
            acc[s] = __builtin_amdgcn_mfma_f32_16x16x32_bf16(a, b, acc[s], 0, 0, 0);
        }
        if (kt < L1W / 32 - 1) {
            int nb = (kt + 1) & 1;
            int cl = tid >> 2, pp = tid & 3;
            *(short8*)(&Bs[nb][cl * 32 + ((pp ^ ((cl >> 1) & 3)) << 3)]) = breg;
        }
        __syncthreads();
    }
    int crow = row0 + kq * 4;
    if (h == 0) {
#pragma unroll
        for (int s = 0; s < 3; s++) {
            int col = s * 16 + m;
#pragma unroll
            for (int r = 0; r < 4; r++) {
                int row = crow + r;
                if (row < N) Ub[(size_t)row * L2WP + col] = f2bf(acc[s][r]);
            }
        }
#pragma unroll
        for (int r = 0; r < 4; r++) {
            int row = crow + r;
            if (row < N) {
                unsigned int u = pack_fp8x4(acc[0][r], acc[1][r], acc[2][r], acc[3][r]);
                *(unsigned int*)(U8 + (size_t)row * 128 + m * 8) = u;
            }
        }
    } else {
#pragma unroll
        for (int r = 0; r < 4; r++) {
            int row = crow + r;
            if (row < N) {
                unsigned int u = pack_fp8x4(acc[0][r], acc[1][r], acc[2][r], acc[3][r]);
                *(unsigned int*)(U8 + (size_t)row * 128 + m * 8 + 4) = u;
            }
        }
    }
}

// ---------------- fused width-256 fp8 prop over Y8 --------------------------

__global__ __launch_bounds__(256) void prop256f_k(const unsigned char* __restrict__ Y8,
                                                  unsigned short* __restrict__ Hb,
                                                  unsigned char* __restrict__ T8,
                                                  const int* __restrict__ rowptr,
                                                  const unsigned int* __restrict__ csr,
                                                  const float* __restrict__ dinv,
                                                  const float* __restrict__ b1, int n) {
    int wave = threadIdx.x >> 6, lane = threadIdx.x & 63;
    int i = blockIdx.x * 4 + wave;
    if (i >= n) return;
    int beg = rowptr[i], end = rowptr[i + 1];
    float di = dinv[i];
    const unsigned int* sbase = (const unsigned int*)Y8 + lane;  // row stride 64 uints
    unsigned int sv = sbase[(size_t)i * 64];
    float w = di * di;
    f32x2 slo = __builtin_amdgcn_cvt_pk_f32_fp8(sv, false);
    f32x2 shi = __builtin_amdgcn_cvt_pk_f32_fp8(sv, true);
    float a0 = w * slo.x, a1 = w * slo.y, a2 = w * shi.x, a3 = w * shi.y;
    int k = beg;
    for (; k + 7 < end; k += 8) {
        unsigned int rr[8];
        unsigned int vv[8];
#pragma unroll
        for (int e = 0; e < 8; e++) rr[e] = csr[k + e];
#pragma unroll
        for (int e = 0; e < 8; e++) vv[e] = sbase[(size_t)EDGE_S(rr[e]) * 64];
#pragma unroll
        for (int e = 0; e < 8; e++) {
            float we = EDGE_W(rr[e]);
            f32x2 lo = __builtin_amdgcn_cvt_pk_f32_fp8(vv[e], false);
            f32x2 hi = __builtin_amdgcn_cvt_pk_f32_fp8(vv[e], true);
            a0 = fmaf(we, lo.x, a0);
            a1 = fmaf(we, lo.y, a1);
            a2 = fmaf(we, hi.x, a2);
            a3 = fmaf(we, hi.y, a3);
        }
    }
    for (; k < end; k++) {
        unsigned int r0 = csr[k];
        float w0 = EDGE_W(r0);
        unsigned int v0 = sbase[(size_t)EDGE_S(r0) * 64];
        f32x2 lo = __builtin_amdgcn_cvt_pk_f32_fp8(v0, false);
        f32x2 hi = __builtin_amdgcn_cvt_pk_f32_fp8(v0, true);
        a0 = fmaf(w0, lo.x, a0); a1 = fmaf(w0, lo.y, a1);
        a2 = fmaf(w0, hi.x, a2); a3 = fmaf(w0, hi.y, a3);
    }
    int m = lane >> 2, jj = lane & 3;
    if (jj < 2) {  // z1: logical cols L_j = (4*jj+j)*16 + m
        float av[4] = {a0, a1, a2, a3};
#pragma unroll
        for (int j = 0; j < 4; j++) {
            int L = (4 * jj + j) * 16 + m;
            Hb[(size_t)i * L1W + 128 + L] = f2bf(fmaxf(av[j] + b1[128 + L], 0.f));
        }
    } else {       // t2 -> T8 phys = m*8 + 4*(jj-2)
        unsigned int o = pack_fp8x4(a0, a1, a2, a3);
        *(unsigned int*)(T8 + (size_t)i * 128 + m * 8 + 4 * (jj - 2)) = o;
    }
}

// ---------------- width-128 fp8 prop: Hb[:,256:384] = relu(P(T8)+b1) --------

__global__ __launch_bounds__(256) void prop128f_k(const unsigned char* __restrict__ T8,
                                                  unsigned short* __restrict__ Hb,
                                                  const int* __restrict__ rowptr,
                                                  const unsigned int* __restrict__ csr,
                                                  const float* __restrict__ dinv,
                                                  const float* __restrict__ b1, int n) {
    int wave = threadIdx.x >> 6, lane = threadIdx.x & 63;
    int i = blockIdx.x * 4 + wave;
    if (i >= n) return;
    int beg = rowptr[i], end = rowptr[i + 1];
    float di = dinv[i];
    const unsigned short* sbase = (const unsigned short*)T8 + lane;  // row stride 64
    unsigned int sv = sbase[(size_t)i * 64];
    float w = di * di;
    f32x2 sd = __builtin_amdgcn_cvt_pk_f32_fp8(sv, false);
    float a0 = w * sd.x, a1 = w * sd.y;
    int k = beg;
    for (; k + 7 < end; k += 8) {
        unsigned int rr[8];
        unsigned int vv[8];
#pragma unroll
        for (int e = 0; e < 8; e++) rr[e] = csr[k + e];
#pragma unroll
        for (int e = 0; e < 8; e++) vv[e] = sbase[(size_t)EDGE_S(rr[e]) * 64];
#pragma unroll
        for (int e = 0; e < 8; e++) {
            float we = EDGE_W(rr[e]);
            f32x2 d = __builtin_amdgcn_cvt_pk_f32_fp8(vv[e], false);
            a0 = fmaf(we, d.x, a0);
            a1 = fmaf(we, d.y, a1);
        }
    }
    for (; k < end; k++) {
        unsigned int r0 = csr[k];
        float w0 = EDGE_W(r0);
        unsigned int v0 = sbase[(size_t)EDGE_S(r0) * 64];
        f32x2 d = __builtin_amdgcn_cvt_pk_f32_fp8(v0, false);
        a0 = fmaf(w0, d.x, a0); a1 = fmaf(w0, d.y, a1);
    }
    int m = lane >> 2, u0 = (2 * lane) & 7;
    int L0 = u0 * 16 + m, L1 = (u0 + 1) * 16 + m;
    Hb[(size_t)i * L1W + 256 + L0] = f2bf(fmaxf(a0 + b1[256 + L0], 0.f));
    Hb[(size_t)i * L1W + 256 + L1] = f2bf(fmaxf(a1 + b1[256 + L1], 0.f));
}

// ---------------- layer-2 prop over U8: 2 edge-groups x 32 cols -------------

__global__ __launch_bounds__(256) void propU8_k(const unsigned char* __restrict__ U8,
                                                unsigned short* __restrict__ T2a,
                                                unsigned char* __restrict__ T8b,
                                                const int* __restrict__ rowptr,
                                                const unsigned int* __restrict__ csr,
                                                const float* __restrict__ dinv, int n) {
    int wave = threadIdx.x >> 6, lane = threadIdx.x & 63;
    int i = blockIdx.x * 4 + wave;
    if (i >= n) return;
    int beg = rowptr[i], end = rowptr[i + 1];
    float di = dinv[i];
    int g = lane >> 5, c = lane & 31;
    const unsigned int* sbase = (const unsigned int*)U8 + c;  // row stride 32 uints
    float a0 = 0.f, a1 = 0.f, a2 = 0.f, a3 = 0.f;
    if (g == 0) {
        unsigned int sv = sbase[(size_t)i * 32];
        float w = di * di;
        f32x2 lo = __builtin_amdgcn_cvt_pk_f32_fp8(sv, false);
        f32x2 hi = __builtin_amdgcn_cvt_pk_f32_fp8(sv, true);
        a0 = w * lo.x; a1 = w * lo.y; a2 = w * hi.x; a3 = w * hi.y;
    }
    int k = beg + g;
    for (; k + 2 < end; k += 4) {
        unsigned int r0 = csr[k], r1 = csr[k + 2];
        unsigned int v0 = sbase[(size_t)EDGE_S(r0) * 32];
        unsigned int v1 = sbase[(size_t)EDGE_S(r1) * 32];
        float w0 = EDGE_W(r0), w1 = EDGE_W(r1);
        f32x2 t;
        t = __builtin_amdgcn_cvt_pk_f32_fp8(v0, false); a0 = fmaf(w0, t.x, a0); a1 = fmaf(w0, t.y, a1);
        t = __builtin_amdgcn_cvt_pk_f32_fp8(v0, true);  a2 = fmaf(w0, t.x, a2); a3 = fmaf(w0, t.y, a3);
        t = __builtin_amdgcn_cvt_pk_f32_fp8(v1, false); a0 = fmaf(w1, t.x, a0); a1 = fmaf(w1, t.y, a1);
        t = __builtin_amdgcn_cvt_pk_f32_fp8(v1, true);  a2 = fmaf(w1, t.x, a2); a3 = fmaf(w1, t.y, a3);
    }
    for (; k < end; k += 2) {
        unsigned int r0 = csr[k];
        float w0 = EDGE_W(r0);
        unsigned int v0 = sbase[(size_t)EDGE_S(r0) * 32];
        f32x2 t;
        t = __builtin_amdgcn_cvt_pk_f32_fp8(v0, false); a0 = fmaf(w0, t.x, a0); a1 = fmaf(w0, t.y, a1);
        t = __builtin_amdgcn_cvt_pk_f32_fp8(v0, true);  a2 = fmaf(w0, t.x, a2); a3 = fmaf(w0, t.y, a3);
    }
    a0 += __shfl_xor(a0, 32, 64);
    a1 += __shfl_xor(a1, 32, 64);
    a2 += __shfl_xor(a2, 32, 64);
    a3 += __shfl_xor(a3, 32, 64);
    if (lane < 32) {
        int m = lane >> 1, sb = 4 * (lane & 1);
        float av[4] = {a0, a1, a2, a3};
#pragma unroll
        for (int j = 0; j < 4; j++) {
            int L = (sb + j) * 16 + m;
            if (L >= 40 && L < 80) T2a[(size_t)i * 40 + (L - 40)] = f2bf(av[j]);
            else if (L >= 80 && L < 120) T8b[(size_t)i * 40 + (L - 80)] = pack_fp8x1(av[j]);
        }
    }
}

// ---------------- fused second-hop prop + log_softmax -----------------------

__global__ __launch_bounds__(256) void lsm_prop_k(const unsigned short* __restrict__ Ub,
                                                  const unsigned short* __restrict__ T2a,
                                                  const unsigned char* __restrict__ T8b,
                                                  const int* __restrict__ rowptr,
                                                  const unsigned int* __restrict__ csr,
                                                  const float* __restrict__ dinv,
                                                  const float* __restrict__ b2,
                                                  float* __restrict__ out, int n) {
    int wave = threadIdx.x >> 6;
    int lane = threadIdx.x & 63;
    int i = blockIdx.x * 4 + wave;
    if (i >= n) return;
    int beg = rowptr[i], end = rowptr[i + 1];
    float di = dinv[i];
    int g = lane / 10;           // 0..6 (lanes 60..63 inactive)
    int c = lane - g * 10;       // 0..9
    bool act = lane < 60;
    const unsigned int* sb = (const unsigned int*)T8b + c;  // row stride 10 uints
    float a0 = 0.f, a1 = 0.f, a2 = 0.f, a3 = 0.f;
    if (lane < 10) {  // self term counted once (group 0)
        unsigned int sv = sb[(size_t)i * 10];
        float w = di * di;
        f32x2 lo = __builtin_amdgcn_cvt_pk_f32_fp8(sv, false);
        f32x2 hi = __builtin_amdgcn_cvt_pk_f32_fp8(sv, true);
        a0 = w * lo.x; a1 = w * lo.y; a2 = w * hi.x; a3 = w * hi.y;
    }
    int k = act ? (beg + g) : end;
    for (; k + 6 < end; k += 12) {
        unsigned int r0 = csr[k], r1 = csr[k + 6];
        unsigned int v0 = sb[(size_t)EDGE_S(r0) * 10];
        unsigned int v1 = sb[(size_t)EDGE_S(r1) * 10];
        float w0 = EDGE_W(r0), w1 = EDGE_W(r1);
        f32x2 t;
        t = __builtin_amdgcn_cvt_pk_f32_fp8(v0, false); a0 = fmaf(w0, t.x, a0); a1 = fmaf(w0, t.y, a1);
        t = __builtin_amdgcn_cvt_pk_f32_fp8(v0, true);  a2 = fmaf(w0, t.x, a2); a3 = fmaf(w0, t.y, a3);
        t = __builtin_amdgcn_cvt_pk_f32_fp8(v1, false); a0 = fmaf(w1, t.x, a0); a1 = fmaf(w1, t.y, a1);
        t = __builtin_amdgcn_cvt_pk_f32_fp8(v1, true);  a2 = fmaf(w1, t.x, a2); a3 = fmaf(w1, t.y, a3);
    }
    for (; k < end; k += 6) {
        unsigned int r0 = csr[k];
        float w0 = EDGE_W(r0);
        unsigned int v0 = sb[(size_t)EDGE_S(r0) * 10];
        f32x2 t;
        t = __builtin_amdgcn_cvt_pk_f32_fp8(v0, false); a0 = fmaf(w0, t.x, a0); a1 = fmaf(w0, t.y, a1);
        t = __builtin_amdgcn_cvt_pk_f32_fp8(v0, true);  a2 = fmaf(w0, t.x, a2); a3 = fmaf(w0, t.y, a3);
    }
    // reduce the 6 group partials into lanes 0..9 (results valid there only)
    float r0s = a0, r1s = a1, r2s = a2, r3s = a3;
#pragma unroll
    for (int g2 = 1; g2 < 6; g2++) {
        r0s += __shfl(a0, lane + 10 * g2, 64);
        r1s += __shfl(a1, lane + 10 * g2, 64);
        r2s += __shfl(a2, lane + 10 * g2, 64);
        r3s += __shfl(a3, lane + 10 * g2, 64);
    }
    // redistribute: lane j1=lane+64 needs col idx=j1-80 from lane idx>>2, comp idx&3
    int j1 = lane + 64;
    int idx = j1 - 80;
    int srcl = (idx < 0) ? 0 : (idx >> 2);
    float s0v = __shfl(r0s, srcl, 64);
    float s1v = __shfl(r1s, srcl, 64);
    float s2v = __shfl(r2s, srcl, 64);
    float s3v = __shfl(r3s, srcl, 64);
    int comp = idx & 3;
    float pv = (comp == 0) ? s0v : (comp == 1) ? s1v : (comp == 2) ? s2v : s3v;
    float v0, v1;
    {
        int j = lane;  // 0..63
        float v = (j >= 40) ? bf2f(T2a[(size_t)i * 40 + (j - 40)]) : bf2f(Ub[(size_t)i * L2WP + j]);
        v0 = v + b2[j];
    }
    if (j1 < 120) {
        float v = (j1 < 80) ? bf2f(T2a[(size_t)i * 40 + (j1 - 40)]) : pv;
        v1 = v + b2[j1];
    } else {
        v1 = -INFINITY;
    }
    float m = fmaxf(v0, v1);
    for (int off = 32; off; off >>= 1) m = fmaxf(m, __shfl_xor(m, off, 64));
    float s = expf(v0 - m) + ((j1 < 120) ? expf(v1 - m) : 0.f);
    for (int off = 32; off; off >>= 1) s += __shfl_xor(s, off, 64);
    float ls = logf(s) + m;
    out[(size_t)i * 120 + lane] = v0 - ls;
    if (j1 < 120) out[(size_t)i * 120 + j1] = v1 - ls;
}

// ---------------- launch ----------------

static inline size_t align256(size_t x) { return (x + 255) & ~(size_t)255; }

extern "C" void kernel_launch(void* const* d_in, const int* in_sizes, int n_in,
                              void* d_out, int out_size, void* d_ws, size_t ws_size,
                              hipStream_t stream) {
    const float* x = (const float*)d_in[0];
    const int* ei = (const int*)d_in[1];
    const float* W1_0 = (const float*)d_in[2];
    const float* W1_1 = (const float*)d_in[3];
    const float* W1_2 = (const float*)d_in[4];
    const float* b1 = (const float*)d_in[5];
    const float* W2_0 = (const float*)d_in[6];
    const float* W2_1 = (const float*)d_in[7];
    const float* W2_2 = (const float*)d_in[8];
    const float* b2 = (const float*)d_in[9];
    float* out = (float*)d_out;

    const int n = N_NODES;
    const int E = in_sizes[1] / 2;
    const int nb = (n + 255) / 256;
    const int nbe4 = ((E + 3) / 4 + 255) / 256;
    const int n2 = NBUK * NBLK1;
    const int nb2 = (n2 + 255) / 256;

    char* p = (char*)d_ws;
    size_t off = 0;
    auto alloc = [&](size_t bytes) {
        void* r = p + off;
        off = align256(off + bytes);
        return r;
    };
    int* flag = (int*)alloc(4);
    int* cnt = (int*)alloc((size_t)n * 4);
    int* rowptr = (int*)alloc((size_t)(n + 1) * 4);
    int* fill = (int*)alloc((size_t)n * 4);
    int* bsum = (int*)alloc((size_t)nb * 4);
    float* dinv = (float*)alloc((size_t)n * 4);
    unsigned int* csr = (unsigned int*)alloc((size_t)E * 4);
    int* cnt2 = (int*)alloc((size_t)n2 * 4);
    int* off2 = (int*)alloc((size_t)n2 * 4);
    int* fill2 = (int*)alloc((size_t)n2 * 4);
    int* bsum2 = (int*)alloc((size_t)nb2 * 4);
    int* tot2 = (int*)alloc(4);
    unsigned int* stage = (unsigned int*)alloc((size_t)E * 4);
    unsigned short* Bp1 = (unsigned short*)alloc((size_t)(F_IN / 32) * L1W * 32 * 2);
    unsigned short* Bp2 = (unsigned short*)alloc((size_t)(L1W / 32) * L2WP * 32 * 2);
    unsigned short* Hb = (unsigned short*)alloc((size_t)n * L1W * 2);
    unsigned char* Y8 = (unsigned char*)alloc((size_t)n * 256);
    unsigned char* T8 = (unsigned char*)alloc((size_t)n * 128);
    unsigned short* Ub = (unsigned short*)alloc((size_t)n * L2WP * 2);
    unsigned char* U8 = (unsigned char*)alloc((size_t)n * 128);
    unsigned short* T2a = (unsigned short*)alloc((size_t)n * C_OUT * 2);
    unsigned char* T8b = (unsigned char*)alloc((size_t)n * C_OUT);
    (void)ws_size;

    // 0. edge dtype detect
    detect_k<<<1, 256, 0, stream>>>(ei, flag);

    // 1. per-node degree + rowptr
    hipMemsetAsync(cnt, 0, (size_t)n * 4, stream);
    hist_k<<<nbe4, 256, 0, stream>>>(ei, flag, cnt, E);
    dinv_k<<<(n + 255) / 256, 256, 0, stream>>>(cnt, dinv, n);
    scan1_k<<<nb, 256, 0, stream>>>(cnt, bsum, n);
    scan2_k<<<1, 256, 0, stream>>>(bsum, rowptr + n, nb);
    scan3_k<<<nb, 256, 0, stream>>>(cnt, bsum, rowptr, fill, n);

    // 2. two-phase binned scatter -> csr
    hist2_k<<<NBLK1, 256, 0, stream>>>(ei, flag, cnt2, E);
    scan1_k<<<nb2, 256, 0, stream>>>(cnt2, bsum2, n2);
    scan2_k<<<1, 256, 0, stream>>>(bsum2, tot2, nb2);
    scan3_k<<<nb2, 256, 0, stream>>>(cnt2, bsum2, off2, fill2, n2);
    stage_k<<<NBLK1, 256, 0, stream>>>(ei, flag, off2, stage, E);
    scatter2_k<<<NBUK, 256, 0, stream>>>(stage, off2, rowptr, dinv, csr, E, n);

    // 3. weight packing
    pack1b_k<<<((F_IN / 32) * L1W * 32 + 255) / 256, 256, 0, stream>>>(W1_0, W1_1, W1_2, Bp1);
    pack2b_k<<<((L1W / 32) * L2WP * 32 + 255) / 256, 256, 0, stream>>>(W2_0, W2_1, W2_2, Bp2);

    // 4. layer 1 GEMM, col-split (z1 -> Hb bf16, y2 -> Y8 fp8 transposed)
    {
        dim3 grid((n + 63) / 64, 2);
        mgemm1_k<<<grid, 256, 0, stream>>>(x, Bp1, b1, Hb, Y8, n);
    }
    prop256f_k<<<(n + 3) / 4, 256, 0, stream>>>(Y8, Hb, T8, rowptr, csr, dinv, b1, n);
    prop128f_k<<<(n + 3) / 4, 256, 0, stream>>>(T8, Hb, rowptr, csr, dinv, b1, n);

    // 5. layer 2 GEMM, col-split -> Ub bf16 (cols<48) + U8 fp8
    {
        dim3 grid((n + 63) / 64, 2);
        mgemm2_k<<<grid, 256, 0, stream>>>(Hb, Bp2, Ub, U8, n);
    }
    propU8_k<<<(n + 3) / 4, 256, 0, stream>>>(U8, T2a, T8b, rowptr, csr, dinv, n);

    // 6. fused second hop + log_softmax
    lsm_prop_k<<<(n + 3) / 4, 256, 0, stream>>>(Ub, T2a, T8b, rowptr, csr, dinv, b2, out, n);
}

// Round 17
// 363.820 us; speedup vs baseline: 1.0869x; 1.0869x over previous
//
#include <hip/hip_runtime.h>
#include <hip/hip_bf16.h>
#include <math.h>

#define N_NODES 50000
#define F_IN 256
#define H1 128
#define C_OUT 40
#define L1W 384   // 3*H1
#define L2W 120   // 3*C_OUT
#define L2WP 128  // padded
#define NBUK 196  // ceil(50000/256) dst buckets of 256 nodes
#define NBLK1 256 // phase-1 blocks

typedef __attribute__((ext_vector_type(8))) short short8;
typedef __attribute__((ext_vector_type(4))) float f32x4;
typedef __attribute__((ext_vector_type(2))) float f32x2;
typedef __attribute__((ext_vector_type(4))) unsigned short us4;

__device__ inline unsigned short f2bf(float f) {
    union { float f; unsigned int u; } x;
    x.f = f;
    unsigned int u = x.u;
    return (unsigned short)((u + 0x7FFF + ((u >> 16) & 1)) >> 16);
}
__device__ inline float bf2f(unsigned short u) {
    union { unsigned int u; float f; } x;
    x.u = (unsigned int)u << 16;
    return x.f;
}
__device__ inline unsigned int pack_fp8x4(float a, float b, float c, float d) {
    int v = 0;
    v = __builtin_amdgcn_cvt_pk_fp8_f32(a, b, v, false);  // bytes 0,1
    v = __builtin_amdgcn_cvt_pk_fp8_f32(c, d, v, true);   // bytes 2,3
    return (unsigned int)v;
}
__device__ inline unsigned char pack_fp8x1(float a) {
    return (unsigned char)(__builtin_amdgcn_cvt_pk_fp8_f32(a, a, 0, false) & 0xFF);
}
// decode 4B edge record {w:bf16:16 | src:16}
#define EDGE_S(r) ((int)((r) & 0xFFFFu))
#define EDGE_W(r) bf2f((unsigned short)((r) >> 16))

// ---------------- edge-index dtype detection --------------------------------

__global__ void detect_k(const int* __restrict__ ei, int* __restrict__ flag) {
    __shared__ int any;
    if (threadIdx.x == 0) any = 0;
    __syncthreads();
    int v = 0;
    for (int r = 0; r < 4; r++) {
        int e = threadIdx.x + r * 256;
        v |= ei[e * 2 + 1];
    }
    if (v != 0) atomicOr(&any, 1);
    __syncthreads();
    if (threadIdx.x == 0) *flag = any;  // 1 => int32 layout, 0 => int64
}

// ---------------- per-node degree histogram ---------------------------------

__global__ void hist_k(const int* __restrict__ ei, const int* __restrict__ flag,
                       int* __restrict__ cnt, int E) {
    int base = (blockIdx.x * 256 + threadIdx.x) * 4;
    if (base >= E) return;
    if (base + 4 <= E) {
        int d0, d1, d2, d3;
        if (*flag) {
            int4 dv = *(const int4*)(ei + E + base);
            d0 = dv.x; d1 = dv.y; d2 = dv.z; d3 = dv.w;
        } else {
            const long long* e64 = (const long long*)ei;
            longlong2 a = *(const longlong2*)(e64 + E + base);
            longlong2 b = *(const longlong2*)(e64 + E + base + 2);
            d0 = (int)a.x; d1 = (int)a.y; d2 = (int)b.x; d3 = (int)b.y;
        }
        atomicAdd(&cnt[d0], 1);
        atomicAdd(&cnt[d1], 1);
        atomicAdd(&cnt[d2], 1);
        atomicAdd(&cnt[d3], 1);
    } else {
        for (int e = base; e < E; e++) {
            int d = (*flag) ? ei[E + e] : (int)((const long long*)ei)[E + e];
            atomicAdd(&cnt[d], 1);
        }
    }
}

// ---------------- generic 3-level exclusive scan ----------------------------

__global__ __launch_bounds__(256) void scan1_k(const int* __restrict__ cnt,
                                               int* __restrict__ bsum, int n) {
    int t = threadIdx.x;
    int i = blockIdx.x * 256 + t;
    int v = (i < n) ? cnt[i] : 0;
    for (int off = 32; off; off >>= 1) v += __shfl_down(v, off, 64);
    __shared__ int ws[4];
    if ((t & 63) == 0) ws[t >> 6] = v;
    __syncthreads();
    if (t == 0) bsum[blockIdx.x] = ws[0] + ws[1] + ws[2] + ws[3];
}

__global__ __launch_bounds__(256) void scan2_k(int* __restrict__ bsum,
                                               int* __restrict__ btot, int nb) {
    __shared__ int s[256];
    int t = threadIdx.x;
    int v = (t < nb) ? bsum[t] : 0;
    s[t] = v;
    __syncthreads();
    for (int off = 1; off < 256; off <<= 1) {
        int u = (t >= off) ? s[t - off] : 0;
        __syncthreads();
        s[t] += u;
        __syncthreads();
    }
    if (t < nb) bsum[t] = s[t] - v;  // exclusive
    if (t == nb - 1) *btot = s[t];
}

// scan3 + optional dinv fusion (dinv != nullptr only for the node scan)
__global__ __launch_bounds__(256) void scan3_k(const int* __restrict__ cnt,
                                               const int* __restrict__ bsum,
                                               int* __restrict__ rowptr,
                                               float* __restrict__ dinv, int n) {
    __shared__ int s[256];
    int t = threadIdx.x;
    int i = blockIdx.x * 256 + t;
    int v = (i < n) ? cnt[i] : 0;
    s[t] = v;
    __syncthreads();
    for (int off = 1; off < 256; off <<= 1) {
        int u = (t >= off) ? s[t - off] : 0;
        __syncthreads();
        s[t] += u;
        __syncthreads();
    }
    if (i < n) {
        rowptr[i] = s[t] - v + bsum[blockIdx.x];
        if (dinv) dinv[i] = rsqrtf((float)v + 1.0f);
    }
}

// ---------------- two-phase binned scatter ----------------------------------

__global__ __launch_bounds__(256) void hist2_k(const int* __restrict__ ei,
                                               const int* __restrict__ flag,
                                               int* __restrict__ cnt2, int E) {
    __shared__ int lcnt[NBUK];
    int t = threadIdx.x, blk = blockIdx.x;
    for (int j = t; j < NBUK; j += 256) lcnt[j] = 0;
    __syncthreads();
    int chunk = (E + NBLK1 - 1) / NBLK1;
    int beg = blk * chunk, end = min(beg + chunk, E);
    bool i32 = (*flag) != 0;
    const long long* e64 = (const long long*)ei;
    for (int e = beg + t; e < end; e += 256) {
        int d = i32 ? ei[E + e] : (int)e64[E + e];
        atomicAdd(&lcnt[d >> 8], 1);
    }
    __syncthreads();
    for (int j = t; j < NBUK; j += 256) cnt2[j * NBLK1 + blk] = lcnt[j];  // bucket-major
}

__global__ __launch_bounds__(256) void stage_k(const int* __restrict__ ei,
                                               const int* __restrict__ flag,
                                               const int* __restrict__ off2,
                                               unsigned int* __restrict__ stage, int E) {
    __shared__ int lcur[NBUK];
    int t = threadIdx.x, blk = blockIdx.x;
    for (int j = t; j < NBUK; j += 256) lcur[j] = off2[j * NBLK1 + blk];
    __syncthreads();
    int chunk = (E + NBLK1 - 1) / NBLK1;
    int beg = blk * chunk, end = min(beg + chunk, E);
    bool i32 = (*flag) != 0;
    const long long* e64 = (const long long*)ei;
    for (int e = beg + t; e < end; e += 256) {
        int s, d;
        if (i32) { s = ei[e]; d = ei[E + e]; }
        else { s = (int)e64[e]; d = (int)e64[E + e]; }
        int b = d >> 8;
        int pos = atomicAdd(&lcur[b], 1);
        stage[pos] = ((unsigned int)(d & 255) << 16) | (unsigned int)s;
    }
}

__global__ __launch_bounds__(256) void scatter2_k(const unsigned int* __restrict__ stage,
                                                  const int* __restrict__ off2,
                                                  const int* __restrict__ rowptr,
                                                  const float* __restrict__ dinv,
                                                  unsigned int* __restrict__ csr,
                                                  int E, int n) {
    __shared__ int lfill[256];
    int b = blockIdx.x, t = threadIdx.x;
    int node0 = b << 8;
    int node = node0 + t;
    lfill[t] = (node < n) ? rowptr[node] : 0;
    __syncthreads();
    int segBeg = off2[b * NBLK1];
    int segEnd = (b == NBUK - 1) ? E : off2[(b + 1) * NBLK1];
    for (int e = segBeg + t; e < segEnd; e += 256) {
        unsigned int rec = stage[e];
        int dl = rec >> 16;
        int s = rec & 0xFFFF;
        int d = node0 + dl;
        float w = dinv[s] * dinv[d];
        int pos = atomicAdd(&lfill[dl], 1);
        csr[pos] = ((unsigned int)f2bf(w) << 16) | (unsigned int)s;
    }
}

// ---------------- weight packing (bf16, B-fragment layout), merged ----------
// idx < N1 -> Bp1; else -> Bp2.

#define N1PACK ((F_IN / 32) * L1W * 32)
#define N2PACK ((L1W / 32) * L2WP * 32)

__global__ void pack_k(const float* __restrict__ w10, const float* __restrict__ w11,
                       const float* __restrict__ w12, const float* __restrict__ w20,
                       const float* __restrict__ w21, const float* __restrict__ w22,
                       unsigned short* __restrict__ Bp1, unsigned short* __restrict__ Bp2) {
    int idx = blockIdx.x * 256 + threadIdx.x;
    if (idx < N1PACK) {
        int kk = idx & 31;
        int nn = (idx >> 5) % L1W;
        int kt = idx / (L1W * 32);
        int k = kt * 32 + kk;
        int p = nn >> 7, c = nn & 127;
        const float* w = (p == 0) ? w10 : (p == 1) ? w11 : w12;
        Bp1[idx] = f2bf(w[k * H1 + c]);
    } else if (idx < N1PACK + N2PACK) {
        int j = idx - N1PACK;
        int kk = j & 31;
        int nn = (j >> 5) & (L2WP - 1);
        int kt = j >> 12;  // 128*32 = 4096
        int k = kt * 32 + kk;
        unsigned short v = 0;
        if (nn < L2W) {
            int p = nn / 40, c = nn % 40;
            const float* w = (p == 0) ? w20 : (p == 1) ? w21 : w22;
            v = f2bf(w[k * C_OUT + c]);
        }
        Bp2[j] = v;
    }
}

// ---------------- layer-1 GEMM: LDS-staged B, fused cvt + bias/relu ---------
// cols 0:128 -> relu(+b1) bf16 -> Hb[:,0:128]
// cols 128:384 -> fp8 Y8 [n x 256 B], transposed phys: byte = m*16 + (s-8)

__global__ __launch_bounds__(256, 3) void mgemm1_k(const float* __restrict__ A,
                                                   const unsigned short* __restrict__ Bp,
                                                   const float* __restrict__ b1,
                                                   unsigned short* __restrict__ Hb,
                                                   unsigned char* __restrict__ Y8, int N) {
    __shared__ unsigned short Bs[2][L1W * 32];  // 2 x 24576 B
    int tid = threadIdx.x;
    int wave = tid >> 6, lane = tid & 63;
    int m = lane & 15, kq = lane >> 4;
    int row0 = blockIdx.x * 64 + wave * 16;
    int arow = row0 + m;
    if (arow >= N) arow = N - 1;  // clamped duplicate; stores guarded
    const float* Ap = A + (size_t)arow * F_IN + kq * 8;

    f32x4 acc[24];
#pragma unroll
    for (int s = 0; s < 24; s++) acc[s] = (f32x4){0.f, 0.f, 0.f, 0.f};

    short8 breg[6];
    float4 af0, af1;
#pragma unroll
    for (int c = 0; c < 6; c++) {
        int t = tid + c * 256;
        breg[c] = *(const short8*)(Bp + (size_t)t * 8);
    }
    af0 = *(const float4*)(Ap);
    af1 = *(const float4*)(Ap + 4);
#pragma unroll
    for (int c = 0; c < 6; c++) {
        int t = tid + c * 256;
        int col = t >> 2, pp = t & 3;
        *(short8*)(&Bs[0][col * 32 + ((pp ^ ((col >> 1) & 3)) << 3)]) = breg[c];
    }
    __syncthreads();

    for (int kt = 0; kt < F_IN / 32; kt++) {
        short8 a;
        a[0] = (short)f2bf(af0.x); a[1] = (short)f2bf(af0.y);
        a[2] = (short)f2bf(af0.z); a[3] = (short)f2bf(af0.w);
        a[4] = (short)f2bf(af1.x); a[5] = (short)f2bf(af1.y);
        a[6] = (short)f2bf(af1.z); a[7] = (short)f2bf(af1.w);
        if (kt < F_IN / 32 - 1) {
            const unsigned short* Bn = Bp + (size_t)(kt + 1) * L1W * 32;
#pragma unroll
            for (int c = 0; c < 6; c++) {
                int t = tid + c * 256;
                breg[c] = *(const short8*)(Bn + (size_t)t * 8);
            }
            af0 = *(const float4*)(Ap + (kt + 1) * 32);
            af1 = *(const float4*)(Ap + (kt + 1) * 32 + 4);
        }
        const unsigned short* Bbuf = Bs[kt & 1];
#pragma unroll
        for (int s = 0; s < 24; s++) {
            int col = s * 16 + m;
            short8 b = *(const short8*)(&Bbuf[col * 32 + ((kq ^ ((col >> 1) & 3)) << 3)]);
            acc[s] = __builtin_amdgcn_mfma_f32_16x16x32_bf16(a, b, acc[s], 0, 0, 0);
        }
        if (kt < F_IN / 32 - 1) {
            int nb = (kt + 1) & 1;
#pragma unroll
            for (int c = 0; c < 6; c++) {
                int t = tid + c * 256;
                int col = t >> 2, pp = t & 3;
                *(short8*)(&Bs[nb][col * 32 + ((pp ^ ((col >> 1) & 3)) << 3)]) = breg[c];
            }
        }
        __syncthreads();
    }
    int crow = row0 + kq * 4;
#pragma unroll
    for (int s = 0; s < 8; s++) {
        int col = s * 16 + m;
        float bias = b1[col];
#pragma unroll
        for (int r = 0; r < 4; r++) {
            int row = crow + r;
            if (row < N) Hb[(size_t)row * L1W + col] = f2bf(fmaxf(acc[s][r] + bias, 0.f));
        }
    }
#pragma unroll
    for (int r = 0; r < 4; r++) {
        int row = crow + r;
        if (row < N) {
            uint4 u;
            u.x = pack_fp8x4(acc[8][r], acc[9][r], acc[10][r], acc[11][r]);
            u.y = pack_fp8x4(acc[12][r], acc[13][r], acc[14][r], acc[15][r]);
            u.z = pack_fp8x4(acc[16][r], acc[17][r], acc[18][r], acc[19][r]);
            u.w = pack_fp8x4(acc[20][r], acc[21][r], acc[22][r], acc[23][r]);
            *(uint4*)(Y8 + (size_t)row * 256 + m * 16) = u;
        }
    }
}

// ---------------- layer-2 GEMM: LDS-staged B -> Ub bf16 (cols<48) + U8 fp8 --

__global__ __launch_bounds__(256) void mgemm2_k(const unsigned short* __restrict__ A,
                                                const unsigned short* __restrict__ Bp,
                                                unsigned short* __restrict__ Ub,
                                                unsigned char* __restrict__ U8, int N) {
    __shared__ unsigned short Bs[2][L2WP * 32];  // 2 x 8192 B
    int tid = threadIdx.x;
    int wave = tid >> 6, lane = tid & 63;
    int m = lane & 15, kq = lane >> 4;
    int row0 = blockIdx.x * 64 + wave * 16;
    int arow = row0 + m;
    if (arow >= N) arow = N - 1;
    const unsigned short* Ap = A + (size_t)arow * L1W + kq * 8;

    f32x4 acc[8];
#pragma unroll
    for (int s = 0; s < 8; s++) acc[s] = (f32x4){0.f, 0.f, 0.f, 0.f};

    short8 breg[2];
    short8 areg;
#pragma unroll
    for (int c = 0; c < 2; c++) {
        int t = tid + c * 256;
        breg[c] = *(const short8*)(Bp + (size_t)t * 8);
    }
    areg = *(const short8*)(Ap);
#pragma unroll
    for (int c = 0; c < 2; c++) {
        int t = tid + c * 256;
        int col = t >> 2, pp = t & 3;
        *(short8*)(&Bs[0][col * 32 + ((pp ^ ((col >> 1) & 3)) << 3)]) = breg[c];
    }
    __syncthreads();

    for (int kt = 0; kt < L1W / 32; kt++) {
        short8 a = areg;
        if (kt < L1W / 32 - 1) {
            const unsigned short* Bn = Bp + (size_t)(kt + 1) * L2WP * 32;
#pragma unroll
            for (int c = 0; c < 2; c++) {
                int t = tid + c * 256;
                breg[c] = *(const short8*)(Bn + (size_t)t * 8);
            }
            areg = *(const short8*)(Ap + (kt + 1) * 32);
        }
        const unsigned short* Bbuf = Bs[kt & 1];
#pragma unroll
        for (int s = 0; s < 8; s++) {
            int col = s * 16 + m;
            short8 b = *(const short8*)(&Bbuf[col * 32 + ((kq ^ ((col >> 1) & 3)) << 3)]);
            acc[s] = __builtin_amdgcn_mfma_f32_16x16x32_bf16(a, b, acc[s], 0, 0, 0);
        }
        if (kt < L1W / 32 - 1) {
            int nb = (kt + 1) & 1;
#pragma unroll
            for (int c = 0; c < 2; c++) {
                int t = tid + c * 256;
                int col = t >> 2, pp = t & 3;
                *(short8*)(&Bs[nb][col * 32 + ((pp ^ ((col >> 1) & 3)) << 3)]) = breg[c];
            }
        }
        __syncthreads();
    }
    int crow = row0 + kq * 4;
#pragma unroll
    for (int s = 0; s < 3; s++) {
        int col = s * 16 + m;
#pragma unroll
        for (int r = 0; r < 4; r++) {
            int row = crow + r;
            if (row < N) Ub[(size_t)row * L2WP + col] = f2bf(acc[s][r]);
        }
    }
#pragma unroll
    for (int r = 0; r < 4; r++) {
        int row = crow + r;
        if (row < N) {
            uint2 u;
            u.x = pack_fp8x4(acc[0][r], acc[1][r], acc[2][r], acc[3][r]);
            u.y = pack_fp8x4(acc[4][r], acc[5][r], acc[6][r], acc[7][r]);
            *(uint2*)(U8 + (size_t)row * 128 + m * 8) = u;
        }
    }
}

// ---------------- fused width-256 fp8 prop over Y8 --------------------------

__global__ __launch_bounds__(256) void prop256f_k(const unsigned char* __restrict__ Y8,
                                                  unsigned short* __restrict__ Hb,
                                                  unsigned char* __restrict__ T8,
                                                  const int* __restrict__ rowptr,
                                                  const unsigned int* __restrict__ csr,
                                                  const float* __restrict__ dinv,
                                                  const float* __restrict__ b1, int n) {
    int wave = threadIdx.x >> 6, lane = threadIdx.x & 63;
    int i = blockIdx.x * 4 + wave;
    if (i >= n) return;
    int beg = rowptr[i], end = rowptr[i + 1];
    float di = dinv[i];
    const unsigned int* sbase = (const unsigned int*)Y8 + lane;  // row stride 64 uints
    unsigned int sv = sbase[(size_t)i * 64];
    float w = di * di;
    f32x2 slo = __builtin_amdgcn_cvt_pk_f32_fp8(sv, false);
    f32x2 shi = __builtin_amdgcn_cvt_pk_f32_fp8(sv, true);
    float a0 = w * slo.x, a1 = w * slo.y, a2 = w * shi.x, a3 = w * shi.y;
    int k = beg;
    for (; k + 7 < end; k += 8) {
        unsigned int rr[8];
        unsigned int vv[8];
#pragma unroll
        for (int e = 0; e < 8; e++) rr[e] = csr[k + e];
#pragma unroll
        for (int e = 0; e < 8; e++) vv[e] = sbase[(size_t)EDGE_S(rr[e]) * 64];
#pragma unroll
        for (int e = 0; e < 8; e++) {
            float we = EDGE_W(rr[e]);
            f32x2 lo = __builtin_amdgcn_cvt_pk_f32_fp8(vv[e], false);
            f32x2 hi = __builtin_amdgcn_cvt_pk_f32_fp8(vv[e], true);
            a0 = fmaf(we, lo.x, a0);
            a1 = fmaf(we, lo.y, a1);
            a2 = fmaf(we, hi.x, a2);
            a3 = fmaf(we, hi.y, a3);
        }
    }
    for (; k < end; k++) {
        unsigned int r0 = csr[k];
        float w0 = EDGE_W(r0);
        unsigned int v0 = sbase[(size_t)EDGE_S(r0) * 64];
        f32x2 lo = __builtin_amdgcn_cvt_pk_f32_fp8(v0, false);
        f32x2 hi = __builtin_amdgcn_cvt_pk_f32_fp8(v0, true);
        a0 = fmaf(w0, lo.x, a0); a1 = fmaf(w0, lo.y, a1);
        a2 = fmaf(w0, hi.x, a2); a3 = fmaf(w0, hi.y, a3);
    }
    int m = lane >> 2, jj = lane & 3;
    if (jj < 2) {  // z1: logical cols L_j = (4*jj+j)*16 + m
        float av[4] = {a0, a1, a2, a3};
#pragma unroll
        for (int j = 0; j < 4; j++) {
            int L = (4 * jj + j) * 16 + m;
            Hb[(size_t)i * L1W + 128 + L] = f2bf(fmaxf(av[j] + b1[128 + L], 0.f));
        }
    } else {       // t2 -> T8 phys = m*8 + 4*(jj-2)
        unsigned int o = pack_fp8x4(a0, a1, a2, a3);
        *(unsigned int*)(T8 + (size_t)i * 128 + m * 8 + 4 * (jj - 2)) = o;
    }
}

// ---------------- width-128 fp8 prop: Hb[:,256:384] = relu(P(T8)+b1) --------

__global__ __launch_bounds__(256) void prop128f_k(const unsigned char* __restrict__ T8,
                                                  unsigned short* __restrict__ Hb,
                                                  const int* __restrict__ rowptr,
                                                  const unsigned int* __restrict__ csr,
                                                  const float* __restrict__ dinv,
                                                  const float* __restrict__ b1, int n) {
    int wave = threadIdx.x >> 6, lane = threadIdx.x & 63;
    int i = blockIdx.x * 4 + wave;
    if (i >= n) return;
    int beg = rowptr[i], end = rowptr[i + 1];
    float di = dinv[i];
    const unsigned short* sbase = (const unsigned short*)T8 + lane;  // row stride 64
    unsigned int sv = sbase[(size_t)i * 64];
    float w = di * di;
    f32x2 sd = __builtin_amdgcn_cvt_pk_f32_fp8(sv, false);
    float a0 = w * sd.x, a1 = w * sd.y;
    int k = beg;
    for (; k + 7 < end; k += 8) {
        unsigned int rr[8];
        unsigned int vv[8];
#pragma unroll
        for (int e = 0; e < 8; e++) rr[e] = csr[k + e];
#pragma unroll
        for (int e = 0; e < 8; e++) vv[e] = sbase[(size_t)EDGE_S(rr[e]) * 64];
#pragma unroll
        for (int e = 0; e < 8; e++) {
            float we = EDGE_W(rr[e]);
            f32x2 d = __builtin_amdgcn_cvt_pk_f32_fp8(vv[e], false);
            a0 = fmaf(we, d.x, a0);
            a1 = fmaf(we, d.y, a1);
        }
    }
    for (; k < end; k++) {
        unsigned int r0 = csr[k];
        float w0 = EDGE_W(r0);
        unsigned int v0 = sbase[(size_t)EDGE_S(r0) * 64];
        f32x2 d = __builtin_amdgcn_cvt_pk_f32_fp8(v0, false);
        a0 = fmaf(w0, d.x, a0); a1 = fmaf(w0, d.y, a1);
    }
    int m = lane >> 2, u0 = (2 * lane) & 7;
    int L0 = u0 * 16 + m, L1 = (u0 + 1) * 16 + m;
    Hb[(size_t)i * L1W + 256 + L0] = f2bf(fmaxf(a0 + b1[256 + L0], 0.f));
    Hb[(size_t)i * L1W + 256 + L1] = f2bf(fmaxf(a1 + b1[256 + L1], 0.f));
}

// ---------------- layer-2 prop over U8: 2 edge-groups x 32 cols -------------

__global__ __launch_bounds__(256) void propU8_k(const unsigned char* __restrict__ U8,
                                                unsigned short* __restrict__ T2a,
                                                unsigned char* __restrict__ T8b,
                                                const int* __restrict__ rowptr,
                                                const unsigned int* __restrict__ csr,
                                                const float* __restrict__ dinv, int n) {
    int wave = threadIdx.x >> 6, lane = threadIdx.x & 63;
    int i = blockIdx.x * 4 + wave;
    if (i >= n) return;
    int beg = rowptr[i], end = rowptr[i + 1];
    float di = dinv[i];
    int g = lane >> 5, c = lane & 31;
    const unsigned int* sbase = (const unsigned int*)U8 + c;  // row stride 32 uints
    float a0 = 0.f, a1 = 0.f, a2 = 0.f, a3 = 0.f;
    if (g == 0) {
        unsigned int sv = sbase[(size_t)i * 32];
        float w = di * di;
        f32x2 lo = __builtin_amdgcn_cvt_pk_f32_fp8(sv, false);
        f32x2 hi = __builtin_amdgcn_cvt_pk_f32_fp8(sv, true);
        a0 = w * lo.x; a1 = w * lo.y; a2 = w * hi.x; a3 = w * hi.y;
    }
    int k = beg + g;
    for (; k + 2 < end; k += 4) {
        unsigned int r0 = csr[k], r1 = csr[k + 2];
        unsigned int v0 = sbase[(size_t)EDGE_S(r0) * 32];
        unsigned int v1 = sbase[(size_t)EDGE_S(r1) * 32];
        float w0 = EDGE_W(r0), w1 = EDGE_W(r1);
        f32x2 t;
        t = __builtin_amdgcn_cvt_pk_f32_fp8(v0, false); a0 = fmaf(w0, t.x, a0); a1 = fmaf(w0, t.y, a1);
        t = __builtin_amdgcn_cvt_pk_f32_fp8(v0, true);  a2 = fmaf(w0, t.x, a2); a3 = fmaf(w0, t.y, a3);
        t = __builtin_amdgcn_cvt_pk_f32_fp8(v1, false); a0 = fmaf(w1, t.x, a0); a1 = fmaf(w1, t.y, a1);
        t = __builtin_amdgcn_cvt_pk_f32_fp8(v1, true);  a2 = fmaf(w1, t.x, a2); a3 = fmaf(w1, t.y, a3);
    }
    for (; k < end; k += 2) {
        unsigned int r0 = csr[k];
        float w0 = EDGE_W(r0);
        unsigned int v0 = sbase[(size_t)EDGE_S(r0) * 32];
        f32x2 t;
        t = __builtin_amdgcn_cvt_pk_f32_fp8(v0, false); a0 = fmaf(w0, t.x, a0); a1 = fmaf(w0, t.y, a1);
        t = __builtin_amdgcn_cvt_pk_f32_fp8(v0, true);  a2 = fmaf(w0, t.x, a2); a3 = fmaf(w0, t.y, a3);
    }
    a0 += __shfl_xor(a0, 32, 64);
    a1 += __shfl_xor(a1, 32, 64);
    a2 += __shfl_xor(a2, 32, 64);
    a3 += __shfl_xor(a3, 32, 64);
    if (lane < 32) {
        int m = lane >> 1, sb = 4 * (lane & 1);
        float av[4] = {a0, a1, a2, a3};
#pragma unroll
        for (int j = 0; j < 4; j++) {
            int L = (sb + j) * 16 + m;
            if (L >= 40 && L < 80) T2a[(size_t)i * 40 + (L - 40)] = f2bf(av[j]);
            else if (L >= 80 && L < 120) T8b[(size_t)i * 40 + (L - 80)] = pack_fp8x1(av[j]);
        }
    }
}

// ---------------- fused second-hop prop + log_softmax -----------------------

__global__ __launch_bounds__(256) void lsm_prop_k(const unsigned short* __restrict__ Ub,
                                                  const unsigned short* __restrict__ T2a,
                                                  const unsigned char* __restrict__ T8b,
                                                  const int* __restrict__ rowptr,
                                                  const unsigned int* __restrict__ csr,
                                                  const float* __restrict__ dinv,
                                                  const float* __restrict__ b2,
                                                  float* __restrict__ out, int n) {
    int wave = threadIdx.x >> 6;
    int lane = threadIdx.x & 63;
    int i = blockIdx.x * 4 + wave;
    if (i >= n) return;
    int beg = rowptr[i], end = rowptr[i + 1];
    float di = dinv[i];
    int g = lane / 10;           // 0..6 (lanes 60..63 inactive)
    int c = lane - g * 10;       // 0..9
    bool act = lane < 60;
    const unsigned int* sb = (const unsigned int*)T8b + c;  // row stride 10 uints
    float a0 = 0.f, a1 = 0.f, a2 = 0.f, a3 = 0.f;
    if (lane < 10) {  // self term counted once (group 0)
        unsigned int sv = sb[(size_t)i * 10];
        float w = di * di;
        f32x2 lo = __builtin_amdgcn_cvt_pk_f32_fp8(sv, false);
        f32x2 hi = __builtin_amdgcn_cvt_pk_f32_fp8(sv, true);
        a0 = w * lo.x; a1 = w * lo.y; a2 = w * hi.x; a3 = w * hi.y;
    }
    int k = act ? (beg + g) : end;
    for (; k + 6 < end; k += 12) {
        unsigned int r0 = csr[k], r1 = csr[k + 6];
        unsigned int v0 = sb[(size_t)EDGE_S(r0) * 10];
        unsigned int v1 = sb[(size_t)EDGE_S(r1) * 10];
        float w0 = EDGE_W(r0), w1 = EDGE_W(r1);
        f32x2 t;
        t = __builtin_amdgcn_cvt_pk_f32_fp8(v0, false); a0 = fmaf(w0, t.x, a0); a1 = fmaf(w0, t.y, a1);
        t = __builtin_amdgcn_cvt_pk_f32_fp8(v0, true);  a2 = fmaf(w0, t.x, a2); a3 = fmaf(w0, t.y, a3);
        t = __builtin_amdgcn_cvt_pk_f32_fp8(v1, false); a0 = fmaf(w1, t.x, a0); a1 = fmaf(w1, t.y, a1);
        t = __builtin_amdgcn_cvt_pk_f32_fp8(v1, true);  a2 = fmaf(w1, t.x, a2); a3 = fmaf(w1, t.y, a3);
    }
    for (; k < end; k += 6) {
        unsigned int r0 = csr[k];
        float w0 = EDGE_W(r0);
        unsigned int v0 = sb[(size_t)EDGE_S(r0) * 10];
        f32x2 t;
        t = __builtin_amdgcn_cvt_pk_f32_fp8(v0, false); a0 = fmaf(w0, t.x, a0); a1 = fmaf(w0, t.y, a1);
        t = __builtin_amdgcn_cvt_pk_f32_fp8(v0, true);  a2 = fmaf(w0, t.x, a2); a3 = fmaf(w0, t.y, a3);
    }
    // reduce the 6 group partials into lanes 0..9 (results valid there only)
    float r0s = a0, r1s = a1, r2s = a2, r3s = a3;
#pragma unroll
    for (int g2 = 1; g2 < 6; g2++) {
        r0s += __shfl(a0, lane + 10 * g2, 64);
        r1s += __shfl(a1, lane + 10 * g2, 64);
        r2s += __shfl(a2, lane + 10 * g2, 64);
        r3s += __shfl(a3, lane + 10 * g2, 64);
    }
    // redistribute: lane j1=lane+64 needs col idx=j1-80 from lane idx>>2, comp idx&3
    int j1 = lane + 64;
    int idx = j1 - 80;
    int srcl = (idx < 0) ? 0 : (idx >> 2);
    float s0v = __shfl(r0s, srcl, 64);
    float s1v = __shfl(r1s, srcl, 64);
    float s2v = __shfl(r2s, srcl, 64);
    float s3v = __shfl(r3s, srcl, 64);
    int comp = idx & 3;
    float pv = (comp == 0) ? s0v : (comp == 1) ? s1v : (comp == 2) ? s2v : s3v;
    float v0, v1;
    {
        int j = lane;  // 0..63
        float v = (j >= 40) ? bf2f(T2a[(size_t)i * 40 + (j - 40)]) : bf2f(Ub[(size_t)i * L2WP + j]);
        v0 = v + b2[j];
    }
    if (j1 < 120) {
        float v = (j1 < 80) ? bf2f(T2a[(size_t)i * 40 + (j1 - 40)]) : pv;
        v1 = v + b2[j1];
    } else {
        v1 = -INFINITY;
    }
    float m = fmaxf(v0, v1);
    for (int off = 32; off; off >>= 1) m = fmaxf(m, __shfl_xor(m, off, 64));
    float s = expf(v0 - m) + ((j1 < 120) ? expf(v1 - m) : 0.f);
    for (int off = 32; off; off >>= 1) s += __shfl_xor(s, off, 64);
    float ls = logf(s) + m;
    out[(size_t)i * 120 + lane] = v0 - ls;
    if (j1 < 120) out[(size_t)i * 120 + j1] = v1 - ls;
}

// ---------------- launch ----------------

static inline size_t align256(size_t x) { return (x + 255) & ~(size_t)255; }

extern "C" void kernel_launch(void* const* d_in, const int* in_sizes, int n_in,
                              void* d_out, int out_size, void* d_ws, size_t ws_size,
                              hipStream_t stream) {
    const float* x = (const float*)d_in[0];
    const int* ei = (const int*)d_in[1];
    const float* W1_0 = (const float*)d_in[2];
    const float* W1_1 = (const float*)d_in[3];
    const float* W1_2 = (const float*)d_in[4];
    const float* b1 = (const float*)d_in[5];
    const float* W2_0 = (const float*)d_in[6];
    const float* W2_1 = (const float*)d_in[7];
    const float* W2_2 = (const float*)d_in[8];
    const float* b2 = (const float*)d_in[9];
    float* out = (float*)d_out;

    const int n = N_NODES;
    const int E = in_sizes[1] / 2;
    const int nb = (n + 255) / 256;
    const int nbe4 = ((E + 3) / 4 + 255) / 256;
    const int n2 = NBUK * NBLK1;
    const int nb2 = (n2 + 255) / 256;

    char* p = (char*)d_ws;
    size_t off = 0;
    auto alloc = [&](size_t bytes) {
        void* r = p + off;
        off = align256(off + bytes);
        return r;
    };
    int* flag = (int*)alloc(4);
    int* cnt = (int*)alloc((size_t)n * 4);
    int* rowptr = (int*)alloc((size_t)(n + 1) * 4);
    int* bsum = (int*)alloc((size_t)nb * 4);
    float* dinv = (float*)alloc((size_t)n * 4);
    unsigned int* csr = (unsigned int*)alloc((size_t)E * 4);
    int* cnt2 = (int*)alloc((size_t)n2 * 4);
    int* off2 = (int*)alloc((size_t)n2 * 4);
    int* bsum2 = (int*)alloc((size_t)nb2 * 4);
    int* tot2 = (int*)alloc(4);
    unsigned int* stage = (unsigned int*)alloc((size_t)E * 4);
    unsigned short* Bp1 = (unsigned short*)alloc((size_t)N1PACK * 2);
    unsigned short* Bp2 = (unsigned short*)alloc((size_t)N2PACK * 2);
    unsigned short* Hb = (unsigned short*)alloc((size_t)n * L1W * 2);
    unsigned char* Y8 = (unsigned char*)alloc((size_t)n * 256);
    unsigned char* T8 = (unsigned char*)alloc((size_t)n * 128);
    unsigned short* Ub = (unsigned short*)alloc((size_t)n * L2WP * 2);
    unsigned char* U8 = (unsigned char*)alloc((size_t)n * 128);
    unsigned short* T2a = (unsigned short*)alloc((size_t)n * C_OUT * 2);
    unsigned char* T8b = (unsigned char*)alloc((size_t)n * C_OUT);
    (void)ws_size;

    // 0. edge dtype detect
    detect_k<<<1, 256, 0, stream>>>(ei, flag);

    // 1. per-node degree + rowptr (+dinv fused)
    hipMemsetAsync(cnt, 0, (size_t)n * 4, stream);
    hist_k<<<nbe4, 256, 0, stream>>>(ei, flag, cnt, E);
    scan1_k<<<nb, 256, 0, stream>>>(cnt, bsum, n);
    scan2_k<<<1, 256, 0, stream>>>(bsum, rowptr + n, nb);
    scan3_k<<<nb, 256, 0, stream>>>(cnt, bsum, rowptr, dinv, n);

    // 2. two-phase binned scatter -> csr
    hist2_k<<<NBLK1, 256, 0, stream>>>(ei, flag, cnt2, E);
    scan1_k<<<nb2, 256, 0, stream>>>(cnt2, bsum2, n2);
    scan2_k<<<1, 256, 0, stream>>>(bsum2, tot2, nb2);
    scan3_k<<<nb2, 256, 0, stream>>>(cnt2, bsum2, off2, (float*)nullptr, n2);
    stage_k<<<NBLK1, 256, 0, stream>>>(ei, flag, off2, stage, E);
    scatter2_k<<<NBUK, 256, 0, stream>>>(stage, off2, rowptr, dinv, csr, E, n);

    // 3. weight packing (merged)
    pack_k<<<(N1PACK + N2PACK + 255) / 256, 256, 0, stream>>>(W1_0, W1_1, W1_2,
                                                              W2_0, W2_1, W2_2, Bp1, Bp2);

    // 4. layer 1 GEMM (z1 -> Hb bf16, y2 -> Y8 fp8 transposed)
    mgemm1_k<<<(n + 63) / 64, 256, 0, stream>>>(x, Bp1, b1, Hb, Y8, n);
    prop256f_k<<<(n + 3) / 4, 256, 0, stream>>>(Y8, Hb, T8, rowptr, csr, dinv, b1, n);
    prop128f_k<<<(n + 3) / 4, 256, 0, stream>>>(T8, Hb, rowptr, csr, dinv, b1, n);

    // 5. layer 2 GEMM -> Ub bf16 (cols<48) + U8 fp8 (1 line/row)
    mgemm2_k<<<(n + 63) / 64, 256, 0, stream>>>(Hb, Bp2, Ub, U8, n);
    propU8_k<<<(n + 3) / 4, 256, 0, stream>>>(U8, T2a, T8b, rowptr, csr, dinv, n);

    // 6. fused second hop + log_softmax
    lsm_prop_k<<<(n + 3) / 4, 256, 0, stream>>>(Ub, T2a, T8b, rowptr, csr, dinv, b2, out, n);
}